// Round 7
// baseline (86.830 us; speedup 1.0000x reference)
//
#include <hip/hip_runtime.h>
#include <math.h>

typedef __attribute__((ext_vector_type(8))) short bf16x8;
typedef __attribute__((ext_vector_type(16))) float f32x16;
typedef __attribute__((ext_vector_type(4))) float f32x4;
typedef __attribute__((ext_vector_type(8))) unsigned short us8;

// ws layout (float offsets)
static constexpr size_t WS_WA   = 0;    // 64: wa1[32] ‖ wa2[32]
static constexpr size_t WS_C12  = 64;   // 2: b.a1, b.a2
static constexpr size_t WS_WMF  = 96;   // 1024 u16: stage-1 B frags [kap][l][e] = wm[t][f], t=16kap+8(l>>5)+e, f=l&31
static constexpr size_t WS_ADJF = 608;  // 1024 u16: stage-2 B frags (adj_n, same layout)
static constexpr size_t WS_S1   = 2048;                     // 32768 sites x 32 f32
static constexpr size_t WS_S2   = WS_S1 + (size_t)1048576;
static constexpr size_t WS_DEN  = WS_S2 + (size_t)1048576;  // [nh][i][j] = 1/denom (512 x 1024)

__device__ __forceinline__ unsigned short f2bf(float x){
    union { float f; unsigned u; } c; c.f = x;
    unsigned r = c.u + 0x7FFFu + ((c.u >> 16) & 1u);
    return (unsigned short)(r >> 16);
}
__device__ __forceinline__ unsigned pk2(float a, float b){
    return (unsigned)f2bf(a) | ((unsigned)f2bf(b) << 16);
}
__device__ __forceinline__ float elu(float x){ return x > 0.f ? x : __expf(x) - 1.0f; }
__device__ __forceinline__ float lrelu(float x){ return fmaxf(x, 0.2f * x); }

__global__ __launch_bounds__(1024) void k0_prep(const float* __restrict__ W_map,
    const float* __restrict__ b_map, const float* __restrict__ a_attn,
    const float* __restrict__ B_adj, float* __restrict__ ws)
{
    __shared__ float lds[1024];
    __shared__ float d12[32];
    int tid = threadIdx.x;
    int i = tid >> 5, j = tid & 31;
    float a = B_adj[tid] + (i == j ? 1.0f : 0.0f);
    lds[tid] = a; __syncthreads();
    for (int s = 512; s > 0; s >>= 1) { if (tid < s) lds[tid] = fmaxf(lds[tid], lds[tid + s]); __syncthreads(); }
    float mx = lds[0]; __syncthreads();
    lds[tid] = a; __syncthreads();
    for (int s = 512; s > 0; s >>= 1) { if (tid < s) lds[tid] = fminf(lds[tid], lds[tid + s]); __syncthreads(); }
    float mn = lds[0]; __syncthreads();
    lds[tid] = (a - mn) / (mx - mn); __syncthreads();
    if (tid < 32) {
        float s = 0.f;
        for (int jj = 0; jj < 32; ++jj) s += lds[tid * 32 + jj];
        d12[tid] = 1.0f / sqrtf(s);
    }
    __syncthreads();

    // frag-ordered constants: idx = kap*512 + l*8 + e
    {
        int kap = tid >> 9, rem = tid & 511, l = rem >> 3, e = rem & 7;
        int krow = 16 * kap + 8 * (l >> 5) + e;   // t (for wm) / i (for adj)
        int col  = l & 31;                        // f / i2
        ((unsigned short*)(ws + WS_WMF))[tid] = f2bf(W_map[krow * 32 + col]);
        float aij = B_adj[krow * 32 + col] + (krow == col ? 1.0f : 0.0f);
        float adjv = d12[krow] * ((aij - mn) / (mx - mn)) * d12[col];
        ((unsigned short*)(ws + WS_ADJF))[tid] = f2bf(adjv);
    }
    if (tid < 32) {
        float w1 = 0.f, w2 = 0.f;
        for (int f = 0; f < 32; ++f) {
            w1 += W_map[tid * 32 + f] * a_attn[f];
            w2 += W_map[tid * 32 + f] * a_attn[32 + f];
        }
        ws[WS_WA + tid] = w1; ws[WS_WA + 32 + tid] = w2;
    }
    if (tid == 0) {
        float c1 = 0.f, c2 = 0.f;
        for (int f = 0; f < 32; ++f) { c1 += b_map[f] * a_attn[f]; c2 += b_map[f] * a_attn[32 + f]; }
        ws[WS_C12] = c1; ws[WS_C12 + 1] = c2;
    }
}

// k12: one block = one (n,hh) row. Stream h -> s1/s2 (global + LDS) -> rden.
__global__ __launch_bounds__(1024) void k12(const float* __restrict__ hin, float* __restrict__ ws)
{
    __shared__ float s1L[64 * 32], s2L[64 * 32], waL[64];
    const int tid = threadIdx.x;
    if (tid < 64) waL[tid] = ws[WS_WA + tid];
    const float c1 = ws[WS_C12], c2 = ws[WS_C12 + 1];
    const long nh = blockIdx.x;
    const float* hrow = hin + nh * 65536;
    __syncthreads();

    const int i = tid & 31, s0 = tid >> 5;
#pragma unroll
    for (int its = 0; its < 2; ++its) {
        const int s = s0 + its * 32;
        const float* hp = hrow + s * 1024;
        float a1 = c1, a2 = c2;
#pragma unroll
        for (int t = 0; t < 32; ++t) {
            float x = hp[t * 32 + i];
            a1 = fmaf(x, waL[t], a1);
            a2 = fmaf(x, waL[32 + t], a2);
        }
        s1L[s * 32 + i] = a1; s2L[s * 32 + i] = a2;
        ws[WS_S1 + nh * 2048 + s * 32 + i] = a1;
        ws[WS_S2 + nh * 2048 + s * 32 + i] = a2;
    }
    __syncthreads();

    const int ii = tid >> 5, j = tid & 31;
    float sum = 0.f;
#pragma unroll
    for (int w = 0; w < 64; ++w)
        sum += __expf(lrelu(s1L[w * 32 + ii] + s2L[w * 32 + j]));
    ws[WS_DEN + nh * 1024 + tid] = 1.0f / sum;
}

// D(32x32 mfma, col=l&31) -> next-stage A/B frag (idx=l&31, k=16*KAP+8*hi+e).
template<int KAP>
__device__ __forceinline__ bf16x8 xform(const f32x16& d, int hi){
    unsigned b0 = pk2(d[8*KAP+0], d[8*KAP+1]);
    unsigned b1 = pk2(d[8*KAP+2], d[8*KAP+3]);
    unsigned b2 = pk2(d[8*KAP+4], d[8*KAP+5]);
    unsigned b3 = pk2(d[8*KAP+6], d[8*KAP+7]);
    unsigned pb0 = (unsigned)__shfl_xor((int)b0, 32, 64);
    unsigned pb1 = (unsigned)__shfl_xor((int)b1, 32, 64);
    unsigned pb2 = (unsigned)__shfl_xor((int)b2, 32, 64);
    unsigned pb3 = (unsigned)__shfl_xor((int)b3, 32, 64);
    union { unsigned u[4]; bf16x8 v; } t;
    t.u[0] = hi ? pb2 : b0;
    t.u[1] = hi ? pb3 : b1;
    t.u[2] = hi ? b2 : pb0;
    t.u[3] = hi ? b3 : pb1;
    return t.v;
}

// kmain: one block = quarter row (16 sites). 36KB LDS -> 4 blocks/CU.
__global__ __launch_bounds__(512, 4) void kmain(const float* __restrict__ hin,
    const float* __restrict__ b_map, const float* __restrict__ ws, float* __restrict__ out)
{
    __shared__ unsigned short hbf[16 * 1024];   // 32 KB, frag order per site
    __shared__ float rdenL[1024];               // 4 KB

    const int tid = threadIdx.x;
    const int wv = tid >> 6, l = tid & 63;
    const int c = l & 31, hi = l >> 5;
    const int blk = blockIdx.x;
    const long nh = blk >> 2;
    const int qr = blk & 3;
    const int hh = (int)(nh & 63), n = (int)(nh >> 6);

    rdenL[tid]       = ws[WS_DEN + nh * 1024 + tid];
    rdenL[tid + 512] = ws[WS_DEN + nh * 1024 + tid + 512];

    // stage 16 sites of h -> bf16 frags. Each lane: 8 stride-32 coalesced loads
    // -> one contiguous b128 LDS write (conflict-free).
    {
        const float* hq = hin + nh * 65536 + qr * 16384;
        const int v = tid & 31;
#pragma unroll
        for (int it = 0; it < 4; ++it) {
            const int gid = (it * 512 + tid) >> 5;
            const int site = gid >> 2, kap = (gid >> 1) & 1, hw = gid & 1;
            const float* hp = hq + site * 1024 + (16 * kap + 8 * hw) * 32 + v;
            float x[8];
#pragma unroll
            for (int e = 0; e < 8; ++e) x[e] = hp[e * 32];
            union { unsigned u[4]; us8 v8; } pk;
            pk.u[0] = pk2(x[0], x[1]); pk.u[1] = pk2(x[2], x[3]);
            pk.u[2] = pk2(x[4], x[5]); pk.u[3] = pk2(x[6], x[7]);
            *(us8*)(hbf + site * 1024 + kap * 512 + (v + 32 * hw) * 8) = pk.v8;
        }
    }

    bf16x8 B1f[2], B2f[2];
    {
        const unsigned short* wmf = (const unsigned short*)(ws + WS_WMF);
        const unsigned short* adf = (const unsigned short*)(ws + WS_ADJF);
        B1f[0] = *(const bf16x8*)(wmf + l * 8);
        B1f[1] = *(const bf16x8*)(wmf + 512 + l * 8);
        B2f[0] = *(const bf16x8*)(adf + l * 8);
        B2f[1] = *(const bf16x8*)(adf + 512 + l * 8);
    }
    const float bc = b_map[c];
    __syncthreads();

    const int hh5 = hh >> 5, f3 = hh & 31;
#pragma unroll 1
    for (int k = 0; k < 2; ++k) {
        const int ls = wv * 2 + k;
        const int gw = qr * 16 + ls;
        const long site = nh * 64 + gw;
        const unsigned short* fp = hbf + ls * 1024;
        bf16x8 a10 = *(const bf16x8*)(fp + l * 8);
        bf16x8 a11 = *(const bf16x8*)(fp + 512 + l * 8);

        // stage 1: D1[j][f] = sum_t h[t][j] wm[t][f] + b[f]
        f32x16 d1;
#pragma unroll
        for (int r = 0; r < 16; ++r) d1[r] = bc;
        d1 = __builtin_amdgcn_mfma_f32_32x32x16_bf16(a10, B1f[0], d1, 0, 0, 0);
        d1 = __builtin_amdgcn_mfma_f32_32x32x16_bf16(a11, B1f[1], d1, 0, 0, 0);
        bf16x8 A3_0 = xform<0>(d1, hi);
        bf16x8 A3_1 = xform<1>(d1, hi);

        // stage 2: D2[j][i2] = sum_i attn[i,j] adj[i,i2]; attn in-register
        const float* s1p = ws + WS_S1 + site * 32;
        const float s2c = ws[WS_S2 + site * 32 + c];
        f32x4 sa  = *(const f32x4*)(s1p + 8 * hi);
        f32x4 sb  = *(const f32x4*)(s1p + 8 * hi + 4);
        f32x4 sc_ = *(const f32x4*)(s1p + 16 + 8 * hi);
        f32x4 sd  = *(const f32x4*)(s1p + 16 + 8 * hi + 4);
        float q[16];
#pragma unroll
        for (int e = 0; e < 4; ++e) {
            int i0 = 8 * hi + e, i1 = 8 * hi + 4 + e, i2i = 16 + 8 * hi + e, i3 = 16 + 8 * hi + 4 + e;
            q[e]      = __expf(lrelu(sa[e] + s2c)) * rdenL[i0 * 32 + c];
            q[4 + e]  = __expf(lrelu(sb[e] + s2c)) * rdenL[i1 * 32 + c];
            q[8 + e]  = __expf(lrelu(sc_[e] + s2c)) * rdenL[i2i * 32 + c];
            q[12 + e] = __expf(lrelu(sd[e] + s2c)) * rdenL[i3 * 32 + c];
        }
        union { unsigned u[4]; bf16x8 v; } A2_0, A2_1;
        A2_0.u[0] = pk2(q[0], q[1]);   A2_0.u[1] = pk2(q[2], q[3]);
        A2_0.u[2] = pk2(q[4], q[5]);   A2_0.u[3] = pk2(q[6], q[7]);
        A2_1.u[0] = pk2(q[8], q[9]);   A2_1.u[1] = pk2(q[10], q[11]);
        A2_1.u[2] = pk2(q[12], q[13]); A2_1.u[3] = pk2(q[14], q[15]);

        f32x16 d2;
#pragma unroll
        for (int r = 0; r < 16; ++r) d2[r] = 0.f;
        d2 = __builtin_amdgcn_mfma_f32_32x32x16_bf16(A2_0.v, B2f[0], d2, 0, 0, 0);
        d2 = __builtin_amdgcn_mfma_f32_32x32x16_bf16(A2_1.v, B2f[1], d2, 0, 0, 0);
        bf16x8 B3_0 = xform<0>(d2, hi);
        bf16x8 B3_1 = xform<1>(d2, hi);

        // stage 3: D3[f][i2] = sum_j Wh[j][f] M[j][i2]
        f32x16 d3;
#pragma unroll
        for (int r = 0; r < 16; ++r) d3[r] = 0.f;
        d3 = __builtin_amdgcn_mfma_f32_32x32x16_bf16(A3_0, B3_0, d3, 0, 0, 0);
        d3 = __builtin_amdgcn_mfma_f32_32x32x16_bf16(A3_1, B3_1, d3, 0, 0, 0);

        float* ob = out + (((long)(n * 64 + gw) * 64) * 32 + f3) * 32 + c;
#pragma unroll
        for (int r = 0; r < 16; ++r) {
            int f = (r & 3) + 8 * (r >> 2) + 4 * hi;
            __builtin_nontemporal_store(elu(d3[r]), ob + (f * 2 + hh5) * 1024);
        }
    }
}

extern "C" void kernel_launch(void* const* d_in, const int* in_sizes, int n_in,
                              void* d_out, int out_size, void* d_ws, size_t ws_size,
                              hipStream_t stream) {
    (void)in_sizes; (void)n_in; (void)out_size; (void)ws_size;
    const float* hin    = (const float*)d_in[0];
    const float* W_map  = (const float*)d_in[1];
    const float* b_map  = (const float*)d_in[2];
    const float* a_attn = (const float*)d_in[3];
    const float* B_adj  = (const float*)d_in[4];
    float* out = (float*)d_out;
    float* ws  = (float*)d_ws;

    hipLaunchKernelGGL(k0_prep, dim3(1),    dim3(1024), 0, stream, W_map, b_map, a_attn, B_adj, ws);
    hipLaunchKernelGGL(k12,     dim3(512),  dim3(1024), 0, stream, hin, ws);
    hipLaunchKernelGGL(kmain,   dim3(2048), dim3(512),  0, stream, hin, b_map, ws, out);
}